// Round 1
// baseline (1510.651 us; speedup 1.0000x reference)
//
// R1 baseline: pure-f32, correctness-first.
// pipeline: gemm(pre=x@W_enc+b) -> radix-select top64/row (+z scatter) ->
//           invperm -> sparse decode (both prefixes) + per-(b,t) SSE -> reduce.
// ws layout: pre 64MB | tk_idx 256KB | tk_val 256KB | ipos 256KB | part0/1 32KB
#include <hip/hip_runtime.h>
#include <hip/hip_bf16.h>
#include <stdint.h>

#define NB    1024
#define NT    4
#define NDIN  768
#define NSAE  16384
#define NK    64
#define KDIM  3072
#define PFX0  8192

__device__ __forceinline__ unsigned f2key(float f) {
    union { float f; unsigned u; } cv; cv.f = f;
    unsigned u = cv.u;
    return u ^ ((unsigned)((int)u >> 31) | 0x80000000u);  // monotonic float->uint
}

// ---------------- encoder GEMM: pre = x @ W_enc + b_enc ----------------
// A (1024,3072) row-major, B (3072,16384) row-major, 128x128 tile, BK=16,
// 256 thr, 8x8 microtile.
__global__ __launch_bounds__(256) void gemm_pre_kernel(
    const float* __restrict__ A, const float* __restrict__ Bm,
    const float* __restrict__ bias, float* __restrict__ pre)
{
    __shared__ float As[16][128];   // [k][m]
    __shared__ float Bs[16][128];   // [k][n]
    const int bn = blockIdx.x * 128;
    const int bm = blockIdx.y * 128;
    const int tid = threadIdx.x;
    const int tx = tid & 15;
    const int ty = tid >> 4;

    float acc[8][8];
#pragma unroll
    for (int i = 0; i < 8; ++i)
#pragma unroll
        for (int j = 0; j < 8; ++j) acc[i][j] = 0.f;

    for (int k0 = 0; k0 < KDIM; k0 += 16) {
        // A tile 128x16: 512 float4, 2/thread, transpose into As[k][m]
#pragma unroll
        for (int i = 0; i < 2; ++i) {
            const int idx = i * 256 + tid;
            const int r = idx >> 2;
            const int c = (idx & 3) << 2;
            const float4 v = *(const float4*)(A + (size_t)(bm + r) * KDIM + (k0 + c));
            As[c + 0][r] = v.x; As[c + 1][r] = v.y;
            As[c + 2][r] = v.z; As[c + 3][r] = v.w;
        }
        // B tile 16x128: contiguous float4
#pragma unroll
        for (int i = 0; i < 2; ++i) {
            const int idx = i * 256 + tid;
            const int r = idx >> 5;
            const int c = (idx & 31) << 2;
            *(float4*)(&Bs[r][c]) = *(const float4*)(Bm + (size_t)(k0 + r) * NSAE + (bn + c));
        }
        __syncthreads();
#pragma unroll
        for (int kk = 0; kk < 16; ++kk) {
            const float4 a0 = *(const float4*)(&As[kk][ty * 8]);
            const float4 a1 = *(const float4*)(&As[kk][ty * 8 + 4]);
            const float4 b0 = *(const float4*)(&Bs[kk][tx * 8]);
            const float4 b1 = *(const float4*)(&Bs[kk][tx * 8 + 4]);
            const float av[8] = { a0.x, a0.y, a0.z, a0.w, a1.x, a1.y, a1.z, a1.w };
            const float bv[8] = { b0.x, b0.y, b0.z, b0.w, b1.x, b1.y, b1.z, b1.w };
#pragma unroll
            for (int i = 0; i < 8; ++i)
#pragma unroll
                for (int j = 0; j < 8; ++j)
                    acc[i][j] = fmaf(av[i], bv[j], acc[i][j]);
        }
        __syncthreads();
    }

    float bv8[8];
#pragma unroll
    for (int j = 0; j < 8; ++j) bv8[j] = bias[bn + tx * 8 + j];
#pragma unroll
    for (int i = 0; i < 8; ++i) {
        float4 o0, o1;
        o0.x = acc[i][0] + bv8[0]; o0.y = acc[i][1] + bv8[1];
        o0.z = acc[i][2] + bv8[2]; o0.w = acc[i][3] + bv8[3];
        o1.x = acc[i][4] + bv8[4]; o1.y = acc[i][5] + bv8[5];
        o1.z = acc[i][6] + bv8[6]; o1.w = acc[i][7] + bv8[7];
        const size_t off = (size_t)(bm + ty * 8 + i) * NSAE + bn + tx * 8;
        *(float4*)(pre + off) = o0;
        *(float4*)(pre + off + 4) = o1;
    }
}

// ---------------- per-row radix top-64 + z scatter ----------------
// one block per row; exact threshold via 4x8-bit MSB radix passes over
// monotonic keys; ties broken toward smaller index (matches jax top_k set).
__global__ __launch_bounds__(256) void topk_kernel(
    const float* __restrict__ pre,
    int* __restrict__ tk_idx, float* __restrict__ tk_val,
    float* __restrict__ z)
{
    __shared__ unsigned hist[256];
    __shared__ int sel[NK];
    __shared__ int ties[256];
    __shared__ unsigned sh_prefix, sh_want, sh_cnt, sh_tiecnt;

    const int b = blockIdx.x;
    const int tid = threadIdx.x;
    const float* row = pre + (size_t)b * NSAE;
    float* zrow = z + (size_t)b * NSAE;

    // zero this row of z (poison-proof; scatter overwrites below)
    for (int i = tid * 4; i < NSAE; i += 256 * 4)
        *(float4*)(zrow + i) = make_float4(0.f, 0.f, 0.f, 0.f);

    if (tid == 0) { sh_prefix = 0u; sh_want = NK; sh_cnt = 0u; sh_tiecnt = 0u; }
    __syncthreads();

    for (int pass = 0; pass < 4; ++pass) {
        const int shift = 24 - pass * 8;
        const unsigned mask = (pass == 0) ? 0u : (0xFFFFFFFFu << (shift + 8));
        hist[tid] = 0u;
        __syncthreads();
        const unsigned pfx = sh_prefix;
        for (int i = tid; i < NSAE; i += 256) {
            const unsigned k = f2key(row[i]);
            if ((k & mask) == pfx) atomicAdd(&hist[(k >> shift) & 0xFFu], 1u);
        }
        __syncthreads();
        if (tid == 0) {
            const unsigned want = sh_want;
            unsigned cum = 0u;
            int bsel = 0;
            for (int bin = 255; bin >= 0; --bin) {
                const unsigned c = hist[bin];
                if (cum + c >= want) { bsel = bin; break; }
                cum += c;
            }
            sh_prefix |= ((unsigned)bsel << shift);
            sh_want = want - cum;
        }
        __syncthreads();
    }

    const unsigned T = sh_prefix;   // key of 64th-largest
    for (int i = tid; i < NSAE; i += 256) {
        const unsigned k = f2key(row[i]);
        if (k > T) {
            const unsigned s = atomicAdd(&sh_cnt, 1u);
            sel[s] = i;
        } else if (k == T) {
            const unsigned s = atomicAdd(&sh_tiecnt, 1u);
            if (s < 256u) ties[s] = i;
        }
    }
    __syncthreads();
    if (tid == 0) {
        const unsigned tc = sh_tiecnt;
        const int n = (int)(tc < 256u ? tc : 256u);
        for (int a = 1; a < n; ++a) {           // tiny insertion sort
            const int v = ties[a]; int c = a;
            while (c > 0 && ties[c - 1] > v) { ties[c] = ties[c - 1]; --c; }
            ties[c] = v;
        }
        const int base = (int)sh_cnt;
        const int want = (int)sh_want;
        for (int j = 0; j < want && j < n; ++j) sel[base + j] = ties[j];
    }
    __syncthreads();
    if (tid < NK) {
        const int myi = sel[tid];
        int rank = 0;                            // canonical (ascending-idx) order
#pragma unroll 1
        for (int j = 0; j < NK; ++j) rank += (sel[j] < myi) ? 1 : 0;
        const float v = fmaxf(row[myi], 0.f);    // relu
        tk_idx[b * NK + rank] = myi;
        tk_val[b * NK + rank] = v;
        zrow[myi] = v;
    }
}

// ---------------- inverse permutation ----------------
__global__ __launch_bounds__(256) void invperm_kernel(
    const int* __restrict__ perm, int* __restrict__ ipos)
{
    const int i = blockIdx.x * 256 + threadIdx.x;   // t*NSAE + p
    if (i < NT * NSAE) {
        const int t = i >> 14;
        const int p = i & (NSAE - 1);
        ipos[t * NSAE + perm[i]] = p;
    }
}

// ---------------- sparse decode + SSE partials ----------------
// one block per (b,t); both decoders; branch on p<PFX0 is wave-uniform.
__global__ __launch_bounds__(256) void decode_kernel(
    const float* __restrict__ x,
    const int* __restrict__ tk_idx, const float* __restrict__ tk_val,
    const int* __restrict__ ipos,
    const float* __restrict__ Wd0, const float* __restrict__ bd0,
    const float* __restrict__ Wd1, const float* __restrict__ bd1,
    float* __restrict__ xhat, float* __restrict__ part0, float* __restrict__ part1)
{
    const int bt = blockIdx.x;
    const int b = bt >> 2;
    const int t = bt & 3;
    const int tid = threadIdx.x;

    __shared__ int s_p[NK];
    __shared__ float s_v[NK];
    if (tid < NK) {
        const int s = tk_idx[b * NK + tid];
        s_v[tid] = tk_val[b * NK + tid];
        s_p[tid] = ipos[t * NSAE + s];
    }
    __syncthreads();

    float acc0[3], acc1[3];
#pragma unroll
    for (int r = 0; r < 3; ++r) {
        const int d = tid + 256 * r;
        acc0[r] = bd0[t * NDIN + d];
        acc1[r] = bd1[t * NDIN + d];
    }
    for (int j = 0; j < NK; ++j) {
        const int p = s_p[j];
        const float v = s_v[j];
        const float* w1 = Wd1 + ((size_t)p * NT + t) * NDIN;
#pragma unroll
        for (int r = 0; r < 3; ++r) acc1[r] = fmaf(v, w1[tid + 256 * r], acc1[r]);
        if (p < PFX0) {
            const float* w0 = Wd0 + ((size_t)p * NT + t) * NDIN;
#pragma unroll
            for (int r = 0; r < 3; ++r) acc0[r] = fmaf(v, w0[tid + 256 * r], acc0[r]);
        }
    }

    float e0 = 0.f, e1 = 0.f;
#pragma unroll
    for (int r = 0; r < 3; ++r) {
        const int d = tid + 256 * r;
        const float xv = x[(size_t)bt * NDIN + d];
        const float d0 = acc0[r] - xv;
        const float d1 = acc1[r] - xv;
        e0 = fmaf(d0, d0, e0);
        e1 = fmaf(d1, d1, e1);
        xhat[(size_t)bt * NDIN + d] = acc1[r];
    }

    __shared__ float r0[256];
    __shared__ float r1[256];
    r0[tid] = e0; r1[tid] = e1;
    __syncthreads();
    for (int w = 128; w > 0; w >>= 1) {
        if (tid < w) { r0[tid] += r0[tid + w]; r1[tid] += r1[tid + w]; }
        __syncthreads();
    }
    if (tid == 0) { part0[bt] = r0[0]; part1[bt] = r1[0]; }
}

// ---------------- final deterministic loss reduce ----------------
__global__ __launch_bounds__(256) void reduce_kernel(
    const float* __restrict__ part0, const float* __restrict__ part1,
    float* __restrict__ out_total)
{
    __shared__ double red[256];
    const int tid = threadIdx.x;
    double s = 0.0;
    for (int i = tid; i < NB * NT; i += 256)
        s += (double)part0[i] + (double)part1[i];
    red[tid] = s;
    __syncthreads();
    for (int w = 128; w > 0; w >>= 1) {
        if (tid < w) red[tid] += red[tid + w];
        __syncthreads();
    }
    // total = (sum_t mean_b sse0 + sum_t mean_b sse1) / (T*2)
    if (tid == 0) out_total[0] = (float)(red[0] / ((double)NB * (double)(NT * 2)));
}

extern "C" void kernel_launch(void* const* d_in, const int* in_sizes, int n_in,
                              void* d_out, int out_size, void* d_ws, size_t ws_size,
                              hipStream_t stream)
{
    const float* x     = (const float*)d_in[0];
    const float* W_enc = (const float*)d_in[1];
    const float* b_enc = (const float*)d_in[2];
    const float* Wd0   = (const float*)d_in[3];
    const float* bd0   = (const float*)d_in[4];
    const float* Wd1   = (const float*)d_in[5];
    const float* bd1   = (const float*)d_in[6];
    const int*   perm  = (const int*)d_in[7];

    float* out       = (float*)d_out;
    float* out_total = out;
    float* out_xhat  = out + 1;
    float* out_z     = out + 1 + (size_t)NB * NT * NDIN;

    char* ws = (char*)d_ws;
    size_t off = 0;
    float* pre    = (float*)(ws + off); off += (size_t)NB * NSAE * sizeof(float);
    int*   tk_idx = (int*)(ws + off);   off += (size_t)NB * NK * sizeof(int);
    float* tk_val = (float*)(ws + off); off += (size_t)NB * NK * sizeof(float);
    int*   ipos   = (int*)(ws + off);   off += (size_t)NT * NSAE * sizeof(int);
    float* part0  = (float*)(ws + off); off += (size_t)NB * NT * sizeof(float);
    float* part1  = (float*)(ws + off);

    gemm_pre_kernel<<<dim3(NSAE / 128, NB / 128), 256, 0, stream>>>(x, W_enc, b_enc, pre);
    invperm_kernel<<<(NT * NSAE) / 256, 256, 0, stream>>>(perm, ipos);
    topk_kernel<<<NB, 256, 0, stream>>>(pre, tk_idx, tk_val, out_z);
    decode_kernel<<<NB * NT, 256, 0, stream>>>(x, tk_idx, tk_val, ipos,
                                               Wd0, bd0, Wd1, bd1,
                                               out_xhat, part0, part1);
    reduce_kernel<<<1, 256, 0, stream>>>(part0, part1, out_total);
}

// Round 2
// 1507.980 us; speedup vs baseline: 1.0018x; 1.0018x over previous
//
// R1 baseline: pure-f32, correctness-first.
// pipeline: gemm(pre=x@W_enc+b) -> radix-select top64/row (+z scatter) ->
//           invperm -> sparse decode (both prefixes) + per-(b,t) SSE -> reduce.
// ws layout: pre 64MB | tk_idx 256KB | tk_val 256KB | ipos 256KB | part0/1 32KB
#include <hip/hip_runtime.h>
#include <hip/hip_bf16.h>
#include <stdint.h>

#define NB    1024
#define NT    4
#define NDIN  768
#define NSAE  16384
#define NK    64
#define KDIM  3072
#define PFX0  8192

__device__ __forceinline__ unsigned f2key(float f) {
    union { float f; unsigned u; } cv; cv.f = f;
    unsigned u = cv.u;
    return u ^ ((unsigned)((int)u >> 31) | 0x80000000u);  // monotonic float->uint
}

// ---------------- encoder GEMM: pre = x @ W_enc + b_enc ----------------
// A (1024,3072) row-major, B (3072,16384) row-major, 128x128 tile, BK=16,
// 256 thr, 8x8 microtile.
__global__ __launch_bounds__(256) void gemm_pre_kernel(
    const float* __restrict__ A, const float* __restrict__ Bm,
    const float* __restrict__ bias, float* __restrict__ pre)
{
    __shared__ float As[16][128];   // [k][m]
    __shared__ float Bs[16][128];   // [k][n]
    const int bn = blockIdx.x * 128;
    const int bm = blockIdx.y * 128;
    const int tid = threadIdx.x;
    const int tx = tid & 15;
    const int ty = tid >> 4;

    float acc[8][8];
#pragma unroll
    for (int i = 0; i < 8; ++i)
#pragma unroll
        for (int j = 0; j < 8; ++j) acc[i][j] = 0.f;

    for (int k0 = 0; k0 < KDIM; k0 += 16) {
        // A tile 128x16: 512 float4, 2/thread, transpose into As[k][m]
#pragma unroll
        for (int i = 0; i < 2; ++i) {
            const int idx = i * 256 + tid;
            const int r = idx >> 2;
            const int c = (idx & 3) << 2;
            const float4 v = *(const float4*)(A + (size_t)(bm + r) * KDIM + (k0 + c));
            As[c + 0][r] = v.x; As[c + 1][r] = v.y;
            As[c + 2][r] = v.z; As[c + 3][r] = v.w;
        }
        // B tile 16x128: contiguous float4
#pragma unroll
        for (int i = 0; i < 2; ++i) {
            const int idx = i * 256 + tid;
            const int r = idx >> 5;
            const int c = (idx & 31) << 2;
            *(float4*)(&Bs[r][c]) = *(const float4*)(Bm + (size_t)(k0 + r) * NSAE + (bn + c));
        }
        __syncthreads();
#pragma unroll
        for (int kk = 0; kk < 16; ++kk) {
            const float4 a0 = *(const float4*)(&As[kk][ty * 8]);
            const float4 a1 = *(const float4*)(&As[kk][ty * 8 + 4]);
            const float4 b0 = *(const float4*)(&Bs[kk][tx * 8]);
            const float4 b1 = *(const float4*)(&Bs[kk][tx * 8 + 4]);
            const float av[8] = { a0.x, a0.y, a0.z, a0.w, a1.x, a1.y, a1.z, a1.w };
            const float bv[8] = { b0.x, b0.y, b0.z, b0.w, b1.x, b1.y, b1.z, b1.w };
#pragma unroll
            for (int i = 0; i < 8; ++i)
#pragma unroll
                for (int j = 0; j < 8; ++j)
                    acc[i][j] = fmaf(av[i], bv[j], acc[i][j]);
        }
        __syncthreads();
    }

    float bv8[8];
#pragma unroll
    for (int j = 0; j < 8; ++j) bv8[j] = bias[bn + tx * 8 + j];
#pragma unroll
    for (int i = 0; i < 8; ++i) {
        float4 o0, o1;
        o0.x = acc[i][0] + bv8[0]; o0.y = acc[i][1] + bv8[1];
        o0.z = acc[i][2] + bv8[2]; o0.w = acc[i][3] + bv8[3];
        o1.x = acc[i][4] + bv8[4]; o1.y = acc[i][5] + bv8[5];
        o1.z = acc[i][6] + bv8[6]; o1.w = acc[i][7] + bv8[7];
        const size_t off = (size_t)(bm + ty * 8 + i) * NSAE + bn + tx * 8;
        *(float4*)(pre + off) = o0;
        *(float4*)(pre + off + 4) = o1;
    }
}

// ---------------- per-row radix top-64 + z scatter ----------------
// one block per row; exact threshold via 4x8-bit MSB radix passes over
// monotonic keys; ties broken toward smaller index (matches jax top_k set).
__global__ __launch_bounds__(256) void topk_kernel(
    const float* __restrict__ pre,
    int* __restrict__ tk_idx, float* __restrict__ tk_val,
    float* __restrict__ z)
{
    __shared__ unsigned hist[256];
    __shared__ int sel[NK];
    __shared__ int ties[256];
    __shared__ unsigned sh_prefix, sh_want, sh_cnt, sh_tiecnt;

    const int b = blockIdx.x;
    const int tid = threadIdx.x;
    const float* row = pre + (size_t)b * NSAE;
    float* zrow = z + (size_t)b * NSAE;

    // zero this row of z (poison-proof; scatter overwrites below)
    for (int i = tid * 4; i < NSAE; i += 256 * 4)
        *(float4*)(zrow + i) = make_float4(0.f, 0.f, 0.f, 0.f);

    if (tid == 0) { sh_prefix = 0u; sh_want = NK; sh_cnt = 0u; sh_tiecnt = 0u; }
    __syncthreads();

    for (int pass = 0; pass < 4; ++pass) {
        const int shift = 24 - pass * 8;
        const unsigned mask = (pass == 0) ? 0u : (0xFFFFFFFFu << (shift + 8));
        hist[tid] = 0u;
        __syncthreads();
        const unsigned pfx = sh_prefix;
        for (int i = tid; i < NSAE; i += 256) {
            const unsigned k = f2key(row[i]);
            if ((k & mask) == pfx) atomicAdd(&hist[(k >> shift) & 0xFFu], 1u);
        }
        __syncthreads();
        if (tid == 0) {
            const unsigned want = sh_want;
            unsigned cum = 0u;
            int bsel = 0;
            for (int bin = 255; bin >= 0; --bin) {
                const unsigned c = hist[bin];
                if (cum + c >= want) { bsel = bin; break; }
                cum += c;
            }
            sh_prefix |= ((unsigned)bsel << shift);
            sh_want = want - cum;
        }
        __syncthreads();
    }

    const unsigned T = sh_prefix;   // key of 64th-largest
    for (int i = tid; i < NSAE; i += 256) {
        const unsigned k = f2key(row[i]);
        if (k > T) {
            const unsigned s = atomicAdd(&sh_cnt, 1u);
            sel[s] = i;
        } else if (k == T) {
            const unsigned s = atomicAdd(&sh_tiecnt, 1u);
            if (s < 256u) ties[s] = i;
        }
    }
    __syncthreads();
    if (tid == 0) {
        const unsigned tc = sh_tiecnt;
        const int n = (int)(tc < 256u ? tc : 256u);
        for (int a = 1; a < n; ++a) {           // tiny insertion sort
            const int v = ties[a]; int c = a;
            while (c > 0 && ties[c - 1] > v) { ties[c] = ties[c - 1]; --c; }
            ties[c] = v;
        }
        const int base = (int)sh_cnt;
        const int want = (int)sh_want;
        for (int j = 0; j < want && j < n; ++j) sel[base + j] = ties[j];
    }
    __syncthreads();
    if (tid < NK) {
        const int myi = sel[tid];
        int rank = 0;                            // canonical (ascending-idx) order
#pragma unroll 1
        for (int j = 0; j < NK; ++j) rank += (sel[j] < myi) ? 1 : 0;
        const float v = fmaxf(row[myi], 0.f);    // relu
        tk_idx[b * NK + rank] = myi;
        tk_val[b * NK + rank] = v;
        zrow[myi] = v;
    }
}

// ---------------- inverse permutation ----------------
__global__ __launch_bounds__(256) void invperm_kernel(
    const int* __restrict__ perm, int* __restrict__ ipos)
{
    const int i = blockIdx.x * 256 + threadIdx.x;   // t*NSAE + p
    if (i < NT * NSAE) {
        const int t = i >> 14;
        const int p = i & (NSAE - 1);
        ipos[t * NSAE + perm[i]] = p;
    }
}

// ---------------- sparse decode + SSE partials ----------------
// one block per (b,t); both decoders; branch on p<PFX0 is wave-uniform.
__global__ __launch_bounds__(256) void decode_kernel(
    const float* __restrict__ x,
    const int* __restrict__ tk_idx, const float* __restrict__ tk_val,
    const int* __restrict__ ipos,
    const float* __restrict__ Wd0, const float* __restrict__ bd0,
    const float* __restrict__ Wd1, const float* __restrict__ bd1,
    float* __restrict__ xhat, float* __restrict__ part0, float* __restrict__ part1)
{
    const int bt = blockIdx.x;
    const int b = bt >> 2;
    const int t = bt & 3;
    const int tid = threadIdx.x;

    __shared__ int s_p[NK];
    __shared__ float s_v[NK];
    if (tid < NK) {
        const int s = tk_idx[b * NK + tid];
        s_v[tid] = tk_val[b * NK + tid];
        s_p[tid] = ipos[t * NSAE + s];
    }
    __syncthreads();

    float acc0[3], acc1[3];
#pragma unroll
    for (int r = 0; r < 3; ++r) {
        const int d = tid + 256 * r;
        acc0[r] = bd0[t * NDIN + d];
        acc1[r] = bd1[t * NDIN + d];
    }
    for (int j = 0; j < NK; ++j) {
        const int p = s_p[j];
        const float v = s_v[j];
        const float* w1 = Wd1 + ((size_t)p * NT + t) * NDIN;
#pragma unroll
        for (int r = 0; r < 3; ++r) acc1[r] = fmaf(v, w1[tid + 256 * r], acc1[r]);
        if (p < PFX0) {
            const float* w0 = Wd0 + ((size_t)p * NT + t) * NDIN;
#pragma unroll
            for (int r = 0; r < 3; ++r) acc0[r] = fmaf(v, w0[tid + 256 * r], acc0[r]);
        }
    }

    float e0 = 0.f, e1 = 0.f;
#pragma unroll
    for (int r = 0; r < 3; ++r) {
        const int d = tid + 256 * r;
        const float xv = x[(size_t)bt * NDIN + d];
        const float d0 = acc0[r] - xv;
        const float d1 = acc1[r] - xv;
        e0 = fmaf(d0, d0, e0);
        e1 = fmaf(d1, d1, e1);
        xhat[(size_t)bt * NDIN + d] = acc1[r];
    }

    __shared__ float r0[256];
    __shared__ float r1[256];
    r0[tid] = e0; r1[tid] = e1;
    __syncthreads();
    for (int w = 128; w > 0; w >>= 1) {
        if (tid < w) { r0[tid] += r0[tid + w]; r1[tid] += r1[tid + w]; }
        __syncthreads();
    }
    if (tid == 0) { part0[bt] = r0[0]; part1[bt] = r1[0]; }
}

// ---------------- final deterministic loss reduce ----------------
__global__ __launch_bounds__(256) void reduce_kernel(
    const float* __restrict__ part0, const float* __restrict__ part1,
    float* __restrict__ out_total)
{
    __shared__ double red[256];
    const int tid = threadIdx.x;
    double s = 0.0;
    for (int i = tid; i < NB * NT; i += 256)
        s += (double)part0[i] + (double)part1[i];
    red[tid] = s;
    __syncthreads();
    for (int w = 128; w > 0; w >>= 1) {
        if (tid < w) red[tid] += red[tid + w];
        __syncthreads();
    }
    // total = (sum_t mean_b sse0 + sum_t mean_b sse1) / (T*2)
    if (tid == 0) out_total[0] = (float)(red[0] / ((double)NB * (double)(NT * 2)));
}

extern "C" void kernel_launch(void* const* d_in, const int* in_sizes, int n_in,
                              void* d_out, int out_size, void* d_ws, size_t ws_size,
                              hipStream_t stream)
{
    const float* x     = (const float*)d_in[0];
    const float* W_enc = (const float*)d_in[1];
    const float* b_enc = (const float*)d_in[2];
    const float* Wd0   = (const float*)d_in[3];
    const float* bd0   = (const float*)d_in[4];
    const float* Wd1   = (const float*)d_in[5];
    const float* bd1   = (const float*)d_in[6];
    const int*   perm  = (const int*)d_in[7];

    float* out       = (float*)d_out;
    float* out_total = out;
    float* out_xhat  = out + 1;
    float* out_z     = out + 1 + (size_t)NB * NT * NDIN;

    char* ws = (char*)d_ws;
    size_t off = 0;
    float* pre    = (float*)(ws + off); off += (size_t)NB * NSAE * sizeof(float);
    int*   tk_idx = (int*)(ws + off);   off += (size_t)NB * NK * sizeof(int);
    float* tk_val = (float*)(ws + off); off += (size_t)NB * NK * sizeof(float);
    int*   ipos   = (int*)(ws + off);   off += (size_t)NT * NSAE * sizeof(int);
    float* part0  = (float*)(ws + off); off += (size_t)NB * NT * sizeof(float);
    float* part1  = (float*)(ws + off);

    gemm_pre_kernel<<<dim3(NSAE / 128, NB / 128), 256, 0, stream>>>(x, W_enc, b_enc, pre);
    invperm_kernel<<<(NT * NSAE) / 256, 256, 0, stream>>>(perm, ipos);
    topk_kernel<<<NB, 256, 0, stream>>>(pre, tk_idx, tk_val, out_z);
    decode_kernel<<<NB * NT, 256, 0, stream>>>(x, tk_idx, tk_val, ipos,
                                               Wd0, bd0, Wd1, bd1,
                                               out_xhat, part0, part1);
    reduce_kernel<<<1, 256, 0, stream>>>(part0, part1, out_total);
}